// Round 3
// baseline (634.650 us; speedup 1.0000x reference)
//
#include <hip/hip_runtime.h>
#include <stdint.h>

typedef __bf16 bf16;
typedef __attribute__((ext_vector_type(8))) __bf16 bf16x8;
typedef __attribute__((ext_vector_type(4))) float f32x4;

#define LORA_SCALE 0.25f

// ---- 8-element loaders (16B-granule), source dtype generic ----
__device__ __forceinline__ bf16x8 ld8_bf16(const bf16* p) { return *(const bf16x8*)p; }
__device__ __forceinline__ bf16x8 ld8_bf16(const float* p) {
    f32x4 a = *(const f32x4*)p;
    f32x4 b = *(const f32x4*)(p + 4);
    bf16x8 r;
    r[0] = (bf16)a[0]; r[1] = (bf16)a[1]; r[2] = (bf16)a[2]; r[3] = (bf16)a[3];
    r[4] = (bf16)b[0]; r[5] = (bf16)b[1]; r[6] = (bf16)b[2]; r[7] = (bf16)b[3];
    return r;
}
__device__ __forceinline__ void ld8_f32(const bf16* p, float* o) {
    bf16x8 v = *(const bf16x8*)p;
    #pragma unroll
    for (int e = 0; e < 8; e++) o[e] = (float)v[e];
}
__device__ __forceinline__ void ld8_f32(const float* p, float* o) {
    f32x4 a = *(const f32x4*)p;
    f32x4 b = *(const f32x4*)(p + 4);
    o[0] = a[0]; o[1] = a[1]; o[2] = a[2]; o[3] = a[3];
    o[4] = b[0]; o[5] = b[1]; o[6] = b[2]; o[7] = b[3];
}

// t[m][r] = sum_k X[m][k] * Aall[aid][r][k], r=0..3. One wave per row. f32 math.
template<int K, typename XT>
__global__ __launch_bounds__(256)
void lora_down(const XT* __restrict__ X, const float* __restrict__ Aall,
               const int* __restrict__ adapter, float* __restrict__ T)
{
    const int aid = adapter[0];
    const float* Aa = Aall + (int64_t)aid * 4 * K;
    const int wid  = (blockIdx.x * 256 + threadIdx.x) >> 6;
    const int lane = threadIdx.x & 63;
    const XT* xr = X + (int64_t)wid * K;

    float a0 = 0.f, a1 = 0.f, a2 = 0.f, a3 = 0.f;
    #pragma unroll
    for (int it = 0; it < K / 512; it++) {
        const int k = it * 512 + lane * 8;
        float xv[8], r0[8], r1[8], r2[8], r3[8];
        ld8_f32(&xr[k], xv);
        ld8_f32(&Aa[0 * K + k], r0);
        ld8_f32(&Aa[1 * K + k], r1);
        ld8_f32(&Aa[2 * K + k], r2);
        ld8_f32(&Aa[3 * K + k], r3);
        #pragma unroll
        for (int e = 0; e < 8; e++) {
            a0 += xv[e] * r0[e];
            a1 += xv[e] * r1[e];
            a2 += xv[e] * r2[e];
            a3 += xv[e] * r3[e];
        }
    }
    #pragma unroll
    for (int off = 32; off >= 1; off >>= 1) {
        a0 += __shfl_xor(a0, off);
        a1 += __shfl_xor(a1, off);
        a2 += __shfl_xor(a2, off);
        a3 += __shfl_xor(a3, off);
    }
    if (lane == 0) {
        f32x4 t;
        t[0] = a0; t[1] = a1; t[2] = a2; t[3] = a3;
        *(f32x4*)&T[(int64_t)wid * 4] = t;
    }
}

// C[m][n] = act( sum_k A[m][k]*Bm[n][k] + SCALE * sum_r Tlo[m][r]*Blo[aid][n][r] )
// 128x128 tile, BK=64, 4 waves (2x2 of 64x64), 16x16x32 bf16 MFMA.
// A: f32 or bf16 (converted to bf16 during staging). Bm/Blo/Tlo: f32.
// C: bf16 (LDS-transposed coalesced stores) or f32 (direct stores, no final rounding).
template<bool RELU, typename AT, typename CT>
__global__ __launch_bounds__(256, 2)
void gemm_lora(const AT* __restrict__ A,      // [M][K]
               const float* __restrict__ Bm,  // [N][K]  (torch [out,in] layout)
               CT* __restrict__ C,            // [M][N]
               const float* __restrict__ Tlo, // [M][4]
               const float* __restrict__ Blo, // [NUM][N][4]
               const int* __restrict__ adapter,
               int M, int N, int K)
{
    __shared__ bf16 smem[128 * 128];          // 32 KB; staging (then C-transpose if bf16 out)
    bf16* sA = smem;                          // [128][64]
    bf16* sB = smem + 128 * 64;               // [128][64]

    const int tid  = threadIdx.x;
    const int lane = tid & 63;
    const int w    = tid >> 6;
    const int quad = lane >> 4;
    const int l16  = lane & 15;

    const int nBase = blockIdx.x * 128;
    const int mBase = blockIdx.y * 128;
    const int wm = (w >> 1) * 64;
    const int wn = (w & 1) * 64;

    const int ldRow = tid >> 3;               // 0..31
    const int ldCol = (tid & 7) * 8;          // 0,8,...,56

    f32x4 acc[4][4];
    #pragma unroll
    for (int i = 0; i < 4; i++)
        #pragma unroll
        for (int j = 0; j < 4; j++)
            #pragma unroll
            for (int e = 0; e < 4; e++)
                acc[i][j][e] = 0.f;

    const AT*    gA = A  + (int64_t)mBase * K;
    const float* gB = Bm + (int64_t)nBase * K;

    bf16x8 va[4], vb[4];
    #pragma unroll
    for (int i = 0; i < 4; i++) {
        const int row = i * 32 + ldRow;
        va[i] = ld8_bf16(&gA[(int64_t)row * K + ldCol]);
        vb[i] = ld8_bf16(&gB[(int64_t)row * K + ldCol]);
    }

    for (int kt = 0; kt < K; kt += 64) {
        __syncthreads();                      // prior iter's LDS reads done
        #pragma unroll
        for (int i = 0; i < 4; i++) {
            *(bf16x8*)&sA[(i * 32 + ldRow) * 64 + ldCol] = va[i];
            *(bf16x8*)&sB[(i * 32 + ldRow) * 64 + ldCol] = vb[i];
        }
        __syncthreads();

        if (kt + 64 < K) {                    // prefetch next K-tile into regs
            #pragma unroll
            for (int i = 0; i < 4; i++) {
                const int row = i * 32 + ldRow;
                va[i] = ld8_bf16(&gA[(int64_t)row * K + kt + 64 + ldCol]);
                vb[i] = ld8_bf16(&gB[(int64_t)row * K + kt + 64 + ldCol]);
            }
        }

        #pragma unroll
        for (int ks = 0; ks < 2; ks++) {
            bf16x8 af[4], bfv[4];
            #pragma unroll
            for (int i = 0; i < 4; i++)
                af[i] = *(const bf16x8*)&sA[(wm + i * 16 + l16) * 64 + ks * 32 + quad * 8];
            #pragma unroll
            for (int j = 0; j < 4; j++)
                bfv[j] = *(const bf16x8*)&sB[(wn + j * 16 + l16) * 64 + ks * 32 + quad * 8];
            #pragma unroll
            for (int i = 0; i < 4; i++)
                #pragma unroll
                for (int j = 0; j < 4; j++)
                    acc[i][j] = __builtin_amdgcn_mfma_f32_16x16x32_bf16(af[i], bfv[j], acc[i][j], 0, 0, 0);
        }
    }

    // Epilogue: LoRA delta + activation in fp32.
    const int aid = adapter[0];
    const float* Ba = Blo + (int64_t)aid * N * 4;

    f32x4 bv[4];
    #pragma unroll
    for (int j = 0; j < 4; j++) {
        const int f = nBase + wn + j * 16 + l16;
        bv[j] = *(const f32x4*)&Ba[(int64_t)f * 4];
    }

    if constexpr (sizeof(CT) == 2) __syncthreads();   // K-loop LDS reads done before reuse

    #pragma unroll
    for (int i = 0; i < 4; i++) {
        f32x4 tv[4];
        #pragma unroll
        for (int r = 0; r < 4; r++) {
            const int m = mBase + wm + i * 16 + quad * 4 + r;
            tv[r] = *(const f32x4*)&Tlo[(int64_t)m * 4];
        }
        #pragma unroll
        for (int j = 0; j < 4; j++) {
            #pragma unroll
            for (int r = 0; r < 4; r++) {
                const float d = tv[r][0] * bv[j][0] + tv[r][1] * bv[j][1]
                              + tv[r][2] * bv[j][2] + tv[r][3] * bv[j][3];
                float v = acc[i][j][r] + LORA_SCALE * d;
                if (RELU) v = v > 0.f ? v : 0.f;
                if constexpr (sizeof(CT) == 2) {
                    smem[(wm + i * 16 + quad * 4 + r) * 128 + wn + j * 16 + l16] = (bf16)v;
                } else {
                    const int m = mBase + wm + i * 16 + quad * 4 + r;
                    C[(int64_t)m * N + nBase + wn + j * 16 + l16] = v;
                }
            }
        }
    }

    if constexpr (sizeof(CT) == 2) {
        __syncthreads();
        #pragma unroll
        for (int it = 0; it < 8; it++) {
            const int cc  = it * 256 + tid;
            const int row = cc >> 4;
            const int c8  = (cc & 15) * 8;
            const int m   = mBase + row;
            *(bf16x8*)&C[(int64_t)m * N + nBase + c8] = *(const bf16x8*)&smem[row * 128 + c8];
        }
    }
}

extern "C" void kernel_launch(void* const* d_in, const int* in_sizes, int n_in,
                              void* d_out, int out_size, void* d_ws, size_t ws_size,
                              hipStream_t stream) {
    const float* x  = (const float*)d_in[0];
    const float* W1 = (const float*)d_in[1];
    const float* A1 = (const float*)d_in[2];
    const float* B1 = (const float*)d_in[3];
    const float* W2 = (const float*)d_in[4];
    const float* A2 = (const float*)d_in[5];
    const float* B2 = (const float*)d_in[6];
    const int* adapter = (const int*)d_in[7];
    float* out = (float*)d_out;

    const int M = 16384, D = 1024, F = 4096;

    bf16*  h  = (bf16*)d_ws;                                   // M*F bf16 = 128 MiB
    float* t1 = (float*)((char*)d_ws + (size_t)M * F * 2);     // M*4 f32
    float* t2 = t1 + (size_t)M * 4;                            // M*4 f32

    // t1 = x @ A1a^T   (f32 in, f32 math)
    lora_down<1024, float><<<M / 4, 256, 0, stream>>>(x, A1, adapter, t1);
    // h = relu(x @ W1^T + scale * t1 @ B1a^T)  -> bf16 h
    dim3 g1(F / 128, M / 128);
    gemm_lora<true, float, bf16><<<g1, 256, 0, stream>>>(x, W1, h, t1, B1, adapter, M, F, D);
    // t2 = h @ A2a^T   (bf16 h in, f32 math)
    lora_down<4096, bf16><<<M / 4, 256, 0, stream>>>(h, A2, adapter, t2);
    // out = h @ W2^T + scale * t2 @ B2a^T  -> f32 out
    dim3 g2(D / 128, M / 128);
    gemm_lora<false, bf16, float><<<g2, 256, 0, stream>>>(h, W2, out, t2, B2, adapter, M, D, F);
}

// Round 4
// 583.554 us; speedup vs baseline: 1.0876x; 1.0876x over previous
//
#include <hip/hip_runtime.h>
#include <stdint.h>

typedef __bf16 bf16;
typedef __attribute__((ext_vector_type(8))) __bf16 bf16x8;
typedef __attribute__((ext_vector_type(4))) float f32x4;

#define LORA_SCALE 0.25f

// async global->LDS, 16B per lane. LDS dest is wave-uniform base + lane*16.
__device__ __forceinline__ void gload_lds16(const bf16* g, bf16* l) {
    __builtin_amdgcn_global_load_lds(
        (const __attribute__((address_space(1))) uint32_t*)g,
        (__attribute__((address_space(3))) uint32_t*)l,
        16, 0, 0);
}

__device__ __forceinline__ bf16x8 cvt8(const float* p) {
    f32x4 a = *(const f32x4*)p;
    f32x4 b = *(const f32x4*)(p + 4);
    bf16x8 r;
    r[0] = (bf16)a[0]; r[1] = (bf16)a[1]; r[2] = (bf16)a[2]; r[3] = (bf16)a[3];
    r[4] = (bf16)b[0]; r[5] = (bf16)b[1]; r[6] = (bf16)b[2]; r[7] = (bf16)b[3];
    return r;
}

// f32 -> bf16 elementwise, 8 elems/thread. n must be a multiple of 2048.
__global__ __launch_bounds__(256)
void cvt_f32_bf16(const float* __restrict__ in, bf16* __restrict__ out) {
    const int idx = (blockIdx.x * 256 + threadIdx.x) * 8;
    *(bf16x8*)&out[idx] = cvt8(&in[idx]);
}

__device__ __forceinline__ void ld8_f32(const bf16* p, float* o) {
    bf16x8 v = *(const bf16x8*)p;
    #pragma unroll
    for (int e = 0; e < 8; e++) o[e] = (float)v[e];
}
__device__ __forceinline__ void ld8_f32(const float* p, float* o) {
    f32x4 a = *(const f32x4*)p;
    f32x4 b = *(const f32x4*)(p + 4);
    o[0] = a[0]; o[1] = a[1]; o[2] = a[2]; o[3] = a[3];
    o[4] = b[0]; o[5] = b[1]; o[6] = b[2]; o[7] = b[3];
}

// t[m][r] = sum_k X[m][k] * Aall[aid][r][k], r=0..3. One wave per row. f32 math.
// If CVT, also writes Xb[m][k] = (bf16)X[m][k] (fused conversion pass).
template<int K, typename XT, bool CVT>
__global__ __launch_bounds__(256)
void lora_down(const XT* __restrict__ X, const float* __restrict__ Aall,
               const int* __restrict__ adapter, float* __restrict__ T,
               bf16* __restrict__ Xb)
{
    const int aid = adapter[0];
    const float* Aa = Aall + (int64_t)aid * 4 * K;
    const int wid  = (blockIdx.x * 256 + threadIdx.x) >> 6;
    const int lane = threadIdx.x & 63;
    const XT* xr = X + (int64_t)wid * K;

    float a0 = 0.f, a1 = 0.f, a2 = 0.f, a3 = 0.f;
    #pragma unroll
    for (int it = 0; it < K / 512; it++) {
        const int k = it * 512 + lane * 8;
        float xv[8], r0[8], r1[8], r2[8], r3[8];
        ld8_f32(&xr[k], xv);
        ld8_f32(&Aa[0 * K + k], r0);
        ld8_f32(&Aa[1 * K + k], r1);
        ld8_f32(&Aa[2 * K + k], r2);
        ld8_f32(&Aa[3 * K + k], r3);
        if (CVT) {
            bf16x8 xb;
            #pragma unroll
            for (int e = 0; e < 8; e++) xb[e] = (bf16)xv[e];
            *(bf16x8*)&Xb[(int64_t)wid * K + k] = xb;
        }
        #pragma unroll
        for (int e = 0; e < 8; e++) {
            a0 += xv[e] * r0[e];
            a1 += xv[e] * r1[e];
            a2 += xv[e] * r2[e];
            a3 += xv[e] * r3[e];
        }
    }
    #pragma unroll
    for (int off = 32; off >= 1; off >>= 1) {
        a0 += __shfl_xor(a0, off);
        a1 += __shfl_xor(a1, off);
        a2 += __shfl_xor(a2, off);
        a3 += __shfl_xor(a3, off);
    }
    if (lane == 0) {
        f32x4 t;
        t[0] = a0; t[1] = a1; t[2] = a2; t[3] = a3;
        *(f32x4*)&T[(int64_t)wid * 4] = t;
    }
}

// C[m][n] = act( sum_k A[m][k]*Bm[n][k] + SCALE * sum_r Tlo[m][r]*Blo[aid][n][r] )
// 128x128 tile, BK=64, 4 waves (2x2 of 64x64), 16x16x32 bf16 MFMA.
// m97 structure: global_load_lds width-16 staging, 2-barrier K-loop.
template<bool RELU, typename CT>
__global__ __launch_bounds__(256)
void gemm_lora(const bf16* __restrict__ A,    // [M][K] bf16
               const bf16* __restrict__ Bm,   // [N][K] bf16 (torch [out,in])
               CT* __restrict__ C,            // [M][N]
               const float* __restrict__ Tlo, // [M][4]
               const float* __restrict__ Blo, // [NUM][N][4] f32
               const int* __restrict__ adapter,
               int M, int N, int K)
{
    __shared__ bf16 smem[128 * 128];          // 32 KB; staging (then C-transpose if bf16 out)
    bf16* sA = smem;                          // [128][64]
    bf16* sB = smem + 128 * 64;               // [128][64]

    const int tid  = threadIdx.x;
    const int lane = tid & 63;
    const int w    = tid >> 6;
    const int quad = lane >> 4;
    const int l16  = lane & 15;

    const int nBase = blockIdx.x * 128;
    const int mBase = blockIdx.y * 128;
    const int wm = (w >> 1) * 64;
    const int wn = (w & 1) * 64;

    f32x4 acc[4][4];
    #pragma unroll
    for (int i = 0; i < 4; i++)
        #pragma unroll
        for (int j = 0; j < 4; j++)
            #pragma unroll
            for (int e = 0; e < 4; e++)
                acc[i][j][e] = 0.f;

    const bf16* gA = A  + (int64_t)mBase * K;
    const bf16* gB = Bm + (int64_t)nBase * K;
    const int kc8 = (tid & 7) * 8;            // k-offset within 64-wide tile
    const int ldRow = tid >> 3;               // 0..31

    for (int kt = 0; kt < K; kt += 64) {
        // stage 128x64 A-tile and B-tile; lane l of wave w lands at base + l*16B,
        // which equals row (i*32 + w*8 + l/8), col (l%8)*8 of the [128][64] tile.
        #pragma unroll
        for (int i = 0; i < 4; i++) {
            const int row = i * 32 + ldRow;
            gload_lds16(gA + (int64_t)row * K + kt + kc8, sA + (i * 32 + w * 8) * 64);
            gload_lds16(gB + (int64_t)row * K + kt + kc8, sB + (i * 32 + w * 8) * 64);
        }
        __syncthreads();                      // vmcnt drain + all waves staged
        #pragma unroll
        for (int ks = 0; ks < 2; ks++) {
            bf16x8 af[4], bfv[4];
            #pragma unroll
            for (int i = 0; i < 4; i++)
                af[i] = *(const bf16x8*)&sA[(wm + i * 16 + l16) * 64 + ks * 32 + quad * 8];
            #pragma unroll
            for (int j = 0; j < 4; j++)
                bfv[j] = *(const bf16x8*)&sB[(wn + j * 16 + l16) * 64 + ks * 32 + quad * 8];
            #pragma unroll
            for (int i = 0; i < 4; i++)
                #pragma unroll
                for (int j = 0; j < 4; j++)
                    acc[i][j] = __builtin_amdgcn_mfma_f32_16x16x32_bf16(af[i], bfv[j], acc[i][j], 0, 0, 0);
        }
        __syncthreads();                      // LDS reads done before next staging
    }

    // Epilogue: LoRA delta + activation in fp32.
    const int aid = adapter[0];
    const float* Ba = Blo + (int64_t)aid * N * 4;

    f32x4 bv[4];
    #pragma unroll
    for (int j = 0; j < 4; j++) {
        const int f = nBase + wn + j * 16 + l16;
        bv[j] = *(const f32x4*)&Ba[(int64_t)f * 4];
    }

    #pragma unroll
    for (int i = 0; i < 4; i++) {
        f32x4 tv[4];
        #pragma unroll
        for (int r = 0; r < 4; r++) {
            const int m = mBase + wm + i * 16 + quad * 4 + r;
            tv[r] = *(const f32x4*)&Tlo[(int64_t)m * 4];
        }
        #pragma unroll
        for (int j = 0; j < 4; j++) {
            #pragma unroll
            for (int r = 0; r < 4; r++) {
                const float d = tv[r][0] * bv[j][0] + tv[r][1] * bv[j][1]
                              + tv[r][2] * bv[j][2] + tv[r][3] * bv[j][3];
                float v = acc[i][j][r] + LORA_SCALE * d;
                if (RELU) v = v > 0.f ? v : 0.f;
                if constexpr (sizeof(CT) == 2) {
                    smem[(wm + i * 16 + quad * 4 + r) * 128 + wn + j * 16 + l16] = (bf16)v;
                } else {
                    const int m = mBase + wm + i * 16 + quad * 4 + r;
                    C[(int64_t)m * N + nBase + wn + j * 16 + l16] = v;
                }
            }
        }
    }

    if constexpr (sizeof(CT) == 2) {
        __syncthreads();
        #pragma unroll
        for (int it = 0; it < 8; it++) {
            const int cc  = it * 256 + tid;
            const int row = cc >> 4;
            const int c8  = (cc & 15) * 8;
            const int m   = mBase + row;
            *(bf16x8*)&C[(int64_t)m * N + nBase + c8] = *(const bf16x8*)&smem[row * 128 + c8];
        }
    }
}

extern "C" void kernel_launch(void* const* d_in, const int* in_sizes, int n_in,
                              void* d_out, int out_size, void* d_ws, size_t ws_size,
                              hipStream_t stream) {
    const float* x  = (const float*)d_in[0];
    const float* W1 = (const float*)d_in[1];
    const float* A1 = (const float*)d_in[2];
    const float* B1 = (const float*)d_in[3];
    const float* W2 = (const float*)d_in[4];
    const float* A2 = (const float*)d_in[5];
    const float* B2 = (const float*)d_in[6];
    const int* adapter = (const int*)d_in[7];
    float* out = (float*)d_out;

    const int M = 16384, D = 1024, F = 4096;

    // ws layout (max live ~168.5 MiB):
    //   h  : M*F bf16  = 128 MiB
    //   xb : M*D bf16  =  32 MiB
    //   wb : F*D bf16  =   8 MiB   (W1b during GEMM1, then reused for W2b)
    //   t1, t2 : M*4 f32 each
    bf16*  h  = (bf16*)d_ws;
    bf16*  xb = h + (size_t)M * F;
    bf16*  wb = xb + (size_t)M * D;
    float* t1 = (float*)(wb + (size_t)F * D);
    float* t2 = t1 + (size_t)M * 4;

    // t1 = x @ A1a^T  (f32 math), fused: xb = bf16(x)
    lora_down<1024, float, true><<<M / 4, 256, 0, stream>>>(x, A1, adapter, t1, xb);
    // wb = bf16(W1)
    cvt_f32_bf16<<<(F * D) / 2048, 256, 0, stream>>>(W1, wb);
    // h = relu(xb @ wb^T + scale * t1 @ B1a^T)  -> bf16
    dim3 g1(F / 128, M / 128);
    gemm_lora<true, bf16><<<g1, 256, 0, stream>>>(xb, wb, h, t1, B1, adapter, M, F, D);
    // t2 = h @ A2a^T  (bf16 h in, f32 math)
    lora_down<4096, bf16, false><<<M / 4, 256, 0, stream>>>(h, A2, adapter, t2, nullptr);
    // wb = bf16(W2)   (reuse slot; W1b dead after GEMM1)
    cvt_f32_bf16<<<(D * F) / 2048, 256, 0, stream>>>(W2, wb);
    // out = h @ wb^T + scale * t2 @ B2a^T  -> f32
    dim3 g2(D / 128, M / 128);
    gemm_lora<false, float><<<g2, 256, 0, stream>>>(h, wb, out, t2, B2, adapter, M, D, F);
}

// Round 5
// 486.160 us; speedup vs baseline: 1.3054x; 1.2003x over previous
//
#include <hip/hip_runtime.h>
#include <stdint.h>

typedef __bf16 bf16;
typedef __attribute__((ext_vector_type(8))) __bf16 bf16x8;
typedef __attribute__((ext_vector_type(4))) float f32x4;

#define LORA_SCALE 0.25f

// async global->LDS, 16B per lane. LDS dest is wave-uniform base + lane*16.
__device__ __forceinline__ void gload_lds16(const bf16* g, bf16* l) {
    __builtin_amdgcn_global_load_lds(
        (const __attribute__((address_space(1))) uint32_t*)g,
        (__attribute__((address_space(3))) uint32_t*)l,
        16, 0, 0);
}

__device__ __forceinline__ bf16x8 cvt8(const float* p) {
    f32x4 a = *(const f32x4*)p;
    f32x4 b = *(const f32x4*)(p + 4);
    bf16x8 r;
    r[0] = (bf16)a[0]; r[1] = (bf16)a[1]; r[2] = (bf16)a[2]; r[3] = (bf16)a[3];
    r[4] = (bf16)b[0]; r[5] = (bf16)b[1]; r[6] = (bf16)b[2]; r[7] = (bf16)b[3];
    return r;
}

// f32 -> bf16 elementwise, 8 elems/thread. n must be a multiple of 2048.
__global__ __launch_bounds__(256)
void cvt_f32_bf16(const float* __restrict__ in, bf16* __restrict__ out) {
    const int idx = (blockIdx.x * 256 + threadIdx.x) * 8;
    *(bf16x8*)&out[idx] = cvt8(&in[idx]);
}

__device__ __forceinline__ void ld8_f32(const bf16* p, float* o) {
    bf16x8 v = *(const bf16x8*)p;
    #pragma unroll
    for (int e = 0; e < 8; e++) o[e] = (float)v[e];
}
__device__ __forceinline__ void ld8_f32(const float* p, float* o) {
    f32x4 a = *(const f32x4*)p;
    f32x4 b = *(const f32x4*)(p + 4);
    o[0] = a[0]; o[1] = a[1]; o[2] = a[2]; o[3] = a[3];
    o[4] = b[0]; o[5] = b[1]; o[6] = b[2]; o[7] = b[3];
}

// t[m][r] = sum_k X[m][k] * Aall[aid][r][k], r=0..3. One wave per row. f32 math.
// If CVT, also writes Xb[m][k] = (bf16)X[m][k] (fused conversion pass).
template<int K, typename XT, bool CVT>
__global__ __launch_bounds__(256)
void lora_down(const XT* __restrict__ X, const float* __restrict__ Aall,
               const int* __restrict__ adapter, float* __restrict__ T,
               bf16* __restrict__ Xb)
{
    const int aid = adapter[0];
    const float* Aa = Aall + (int64_t)aid * 4 * K;
    const int wid  = (blockIdx.x * 256 + threadIdx.x) >> 6;
    const int lane = threadIdx.x & 63;
    const XT* xr = X + (int64_t)wid * K;

    float a0 = 0.f, a1 = 0.f, a2 = 0.f, a3 = 0.f;
    #pragma unroll
    for (int it = 0; it < K / 512; it++) {
        const int k = it * 512 + lane * 8;
        float xv[8], r0[8], r1[8], r2[8], r3[8];
        ld8_f32(&xr[k], xv);
        ld8_f32(&Aa[0 * K + k], r0);
        ld8_f32(&Aa[1 * K + k], r1);
        ld8_f32(&Aa[2 * K + k], r2);
        ld8_f32(&Aa[3 * K + k], r3);
        if (CVT) {
            bf16x8 xb;
            #pragma unroll
            for (int e = 0; e < 8; e++) xb[e] = (bf16)xv[e];
            *(bf16x8*)&Xb[(int64_t)wid * K + k] = xb;
        }
        #pragma unroll
        for (int e = 0; e < 8; e++) {
            a0 += xv[e] * r0[e];
            a1 += xv[e] * r1[e];
            a2 += xv[e] * r2[e];
            a3 += xv[e] * r3[e];
        }
    }
    #pragma unroll
    for (int off = 32; off >= 1; off >>= 1) {
        a0 += __shfl_xor(a0, off);
        a1 += __shfl_xor(a1, off);
        a2 += __shfl_xor(a2, off);
        a3 += __shfl_xor(a3, off);
    }
    if (lane == 0) {
        f32x4 t;
        t[0] = a0; t[1] = a1; t[2] = a2; t[3] = a3;
        *(f32x4*)&T[(int64_t)wid * 4] = t;
    }
}

// C[m][n] = act( sum_k A[m][k]*Bm[n][k] + SCALE * sum_r Tlo[m][r]*Blo[aid][n][r] )
// Block tile 256x128, BK=64; 4 waves in 2x2, each wave owns a 128x64 sub-tile
// (8x4 grid of 16x16x32 MFMAs). global_load_lds width-16 staging with XOR
// K-chunk swizzle (content permuted within each 128B row; landing contiguous).
template<bool RELU, typename CT>
__global__ __launch_bounds__(256, 2)
void gemm_lora(const bf16* __restrict__ A,    // [M][K] bf16
               const bf16* __restrict__ Bm,   // [N][K] bf16 (torch [out,in])
               CT* __restrict__ C,            // [M][N]
               const float* __restrict__ Tlo, // [M][4]
               const float* __restrict__ Blo, // [NUM][N][4] f32
               const int* __restrict__ adapter,
               int M, int N, int K)
{
    __shared__ bf16 smem[256 * 64 + 128 * 64];   // 48 KB
    bf16* sA = smem;                              // [256][64]
    bf16* sB = smem + 256 * 64;                   // [128][64]

    const int tid  = threadIdx.x;
    const int lane = tid & 63;
    const int w    = tid >> 6;
    const int quad = lane >> 4;
    const int l16  = lane & 15;

    const int nBase = blockIdx.x * 128;
    const int mBase = blockIdx.y * 256;
    const int wm = (w >> 1) * 128;               // 0 or 128
    const int wn = (w & 1) * 64;                 // 0 or 64

    f32x4 acc[8][4];
    #pragma unroll
    for (int i = 0; i < 8; i++)
        #pragma unroll
        for (int j = 0; j < 4; j++)
            #pragma unroll
            for (int e = 0; e < 4; e++)
                acc[i][j][e] = 0.f;

    const bf16* gA = A  + (int64_t)mBase * K;
    const bf16* gB = Bm + (int64_t)nBase * K;
    const int ldRow  = tid >> 3;                 // 0..31
    // LDS position (tid&7) of row r holds global chunk (tid&7) ^ (r&7).
    const int swzCol = ((tid & 7) ^ ((tid >> 3) & 7)) * 8;

    for (int kt = 0; kt < K; kt += 64) {
        #pragma unroll
        for (int i = 0; i < 8; i++)
            gload_lds16(gA + (int64_t)(i * 32 + ldRow) * K + kt + swzCol,
                        sA + (i * 32 + w * 8) * 64);
        #pragma unroll
        for (int i = 0; i < 4; i++)
            gload_lds16(gB + (int64_t)(i * 32 + ldRow) * K + kt + swzCol,
                        sB + (i * 32 + w * 8) * 64);
        __syncthreads();                         // vmcnt drain + all waves staged
        #pragma unroll
        for (int ks = 0; ks < 2; ks++) {
            const int kpos = (((ks * 4 + quad) ^ (l16 & 7))) * 8;  // swizzled chunk
            bf16x8 af[8], bfv[4];
            #pragma unroll
            for (int i = 0; i < 8; i++)
                af[i] = *(const bf16x8*)&sA[(wm + i * 16 + l16) * 64 + kpos];
            #pragma unroll
            for (int j = 0; j < 4; j++)
                bfv[j] = *(const bf16x8*)&sB[(wn + j * 16 + l16) * 64 + kpos];
            #pragma unroll
            for (int i = 0; i < 8; i++)
                #pragma unroll
                for (int j = 0; j < 4; j++)
                    acc[i][j] = __builtin_amdgcn_mfma_f32_16x16x32_bf16(af[i], bfv[j], acc[i][j], 0, 0, 0);
        }
        __syncthreads();                         // LDS reads done before next staging
    }

    // Epilogue: LoRA delta + activation in fp32.
    const int aid = adapter[0];
    const float* Ba = Blo + (int64_t)aid * N * 4;

    f32x4 bv[4];
    #pragma unroll
    for (int j = 0; j < 4; j++) {
        const int f = nBase + wn + j * 16 + l16;
        bv[j] = *(const f32x4*)&Ba[(int64_t)f * 4];
    }

    if constexpr (sizeof(CT) == 2) {
        // Wave-private LDS transpose (72-elem padded rows -> conflict-free),
        // two 64-row groups; no barriers needed (scratch is wave-private and
        // the K-loop's final barrier already passed).
        bf16* scratch = smem + w * (64 * 72);
        #pragma unroll
        for (int g = 0; g < 2; g++) {
            #pragma unroll
            for (int mi2 = 0; mi2 < 4; mi2++) {
                const int mi = g * 4 + mi2;
                f32x4 tv[4];
                #pragma unroll
                for (int r = 0; r < 4; r++) {
                    const int m = mBase + wm + mi * 16 + quad * 4 + r;
                    tv[r] = *(const f32x4*)&Tlo[(int64_t)m * 4];
                }
                #pragma unroll
                for (int j = 0; j < 4; j++) {
                    #pragma unroll
                    for (int r = 0; r < 4; r++) {
                        const float d = tv[r][0] * bv[j][0] + tv[r][1] * bv[j][1]
                                      + tv[r][2] * bv[j][2] + tv[r][3] * bv[j][3];
                        float v = acc[mi][j][r] + LORA_SCALE * d;
                        if (RELU) v = v > 0.f ? v : 0.f;
                        scratch[(mi2 * 16 + quad * 4 + r) * 72 + j * 16 + l16] = (bf16)v;
                    }
                }
            }
            #pragma unroll
            for (int p = 0; p < 8; p++) {
                const int row = p * 8 + (lane >> 3);
                bf16x8 vv = *(const bf16x8*)&scratch[row * 72 + (lane & 7) * 8];
                const int m = mBase + wm + g * 64 + row;
                *(bf16x8*)&C[(int64_t)m * N + nBase + wn + (lane & 7) * 8] = vv;
            }
        }
    } else {
        #pragma unroll
        for (int mi = 0; mi < 8; mi++) {
            f32x4 tv[4];
            #pragma unroll
            for (int r = 0; r < 4; r++) {
                const int m = mBase + wm + mi * 16 + quad * 4 + r;
                tv[r] = *(const f32x4*)&Tlo[(int64_t)m * 4];
            }
            #pragma unroll
            for (int j = 0; j < 4; j++) {
                #pragma unroll
                for (int r = 0; r < 4; r++) {
                    const float d = tv[r][0] * bv[j][0] + tv[r][1] * bv[j][1]
                                  + tv[r][2] * bv[j][2] + tv[r][3] * bv[j][3];
                    float v = acc[mi][j][r] + LORA_SCALE * d;
                    if (RELU) v = v > 0.f ? v : 0.f;
                    const int m = mBase + wm + mi * 16 + quad * 4 + r;
                    C[(int64_t)m * N + nBase + wn + j * 16 + l16] = v;
                }
            }
        }
    }
}

extern "C" void kernel_launch(void* const* d_in, const int* in_sizes, int n_in,
                              void* d_out, int out_size, void* d_ws, size_t ws_size,
                              hipStream_t stream) {
    const float* x  = (const float*)d_in[0];
    const float* W1 = (const float*)d_in[1];
    const float* A1 = (const float*)d_in[2];
    const float* B1 = (const float*)d_in[3];
    const float* W2 = (const float*)d_in[4];
    const float* A2 = (const float*)d_in[5];
    const float* B2 = (const float*)d_in[6];
    const int* adapter = (const int*)d_in[7];
    float* out = (float*)d_out;

    const int M = 16384, D = 1024, F = 4096;

    // ws layout (max live ~168.5 MiB):
    bf16*  h  = (bf16*)d_ws;                       // M*F bf16 = 128 MiB
    bf16*  xb = h + (size_t)M * F;                 // M*D bf16 =  32 MiB
    bf16*  wb = xb + (size_t)M * D;                // F*D bf16 =   8 MiB (W1b then W2b)
    float* t1 = (float*)(wb + (size_t)F * D);
    float* t2 = t1 + (size_t)M * 4;

    // t1 = x @ A1a^T  (f32 math), fused: xb = bf16(x)
    lora_down<1024, float, true><<<M / 4, 256, 0, stream>>>(x, A1, adapter, t1, xb);
    // wb = bf16(W1)
    cvt_f32_bf16<<<(F * D) / 2048, 256, 0, stream>>>(W1, wb);
    // h = relu(xb @ wb^T + scale * t1 @ B1a^T)  -> bf16
    dim3 g1(F / 128, M / 256);
    gemm_lora<true, bf16><<<g1, 256, 0, stream>>>(xb, wb, h, t1, B1, adapter, M, F, D);
    // t2 = h @ A2a^T  (bf16 h in, f32 math)
    lora_down<4096, bf16, false><<<M / 4, 256, 0, stream>>>(h, A2, adapter, t2, nullptr);
    // wb = bf16(W2)   (reuse slot; W1b dead after GEMM1)
    cvt_f32_bf16<<<(D * F) / 2048, 256, 0, stream>>>(W2, wb);
    // out = h @ wb^T + scale * t2 @ B2a^T  -> f32
    dim3 g2(D / 128, M / 256);
    gemm_lora<false, float><<<g2, 256, 0, stream>>>(h, wb, out, t2, B2, adapter, M, D, F);
}